// Round 7
// baseline (923.948 us; speedup 1.0000x reference)
//
#include <hip/hip_runtime.h>

typedef unsigned short u16;
typedef unsigned int   u32;
typedef unsigned long long u64;
typedef __attribute__((ext_vector_type(8))) __bf16 bf16x8;
typedef __attribute__((ext_vector_type(4))) float  f32x4;

#define TOK 8192
#define DIM 1024
#define NE  16
#define NF  4096
#define CAP 512

// ---------- helpers ----------
__device__ __forceinline__ u16 f2bf(float f) {
    u32 u = __float_as_uint(f);
    u32 r = (u + 0x7FFFu + ((u >> 16) & 1u)) >> 16;   // RNE
    return (u16)r;
}

__device__ __forceinline__ float gelu_tanh(float x) {
    float u = 0.7978845608028654f * (x + 0.044715f * x * x * x);
    float t = __expf(-2.f * fabsf(u));
    float th = (1.f - t) / (1.f + t);
    th = (u < 0.f) ? -th : th;
    return 0.5f * x * (1.f + th);
}

__device__ __forceinline__ void gld16(const void* g, void* l) {
    __builtin_amdgcn_global_load_lds(
        (const __attribute__((address_space(1))) void*)g,
        (__attribute__((address_space(3))) void*)l, 16, 0, 0);
}

// ---------- small kernels ----------
__global__ void moe_wgT(const float* __restrict__ wg, float* __restrict__ wgT,
                        float* __restrict__ me_sums) {
    int i = blockIdx.x * 256 + threadIdx.x;     // 16384 elements
    if (i < NE) me_sums[i] = 0.f;
    int d = i >> 4, e = i & 15;
    wgT[(size_t)e * DIM + d] = wg[i];
}

// one thread per (token, expert); 256 thr = 16 tokens x 16 experts
__global__ void moe_gate(const float* __restrict__ x, const float* __restrict__ wgT,
                         int* __restrict__ eidx, float* __restrict__ gp,
                         float* __restrict__ me_sums) {
    __shared__ float lme[NE];
    const int tid = threadIdx.x;
    if (tid < NE) lme[tid] = 0.f;
    __syncthreads();
    const int tok = blockIdx.x * 16 + (tid >> 4);
    const int e   = tid & 15;
    const float4* xp = (const float4*)(x + (size_t)tok * DIM);
    const float4* wp = (const float4*)(wgT + (size_t)e * DIM);
    float acc = 0.f;
#pragma unroll 4
    for (int i = 0; i < DIM / 4; ++i) {
        float4 a = xp[i], b = wp[i];
        acc = fmaf(a.x, b.x, acc); acc = fmaf(a.y, b.y, acc);
        acc = fmaf(a.z, b.z, acc); acc = fmaf(a.w, b.w, acc);
    }
    float mx = acc;
    for (int off = 8; off; off >>= 1) mx = fmaxf(mx, __shfl_xor(mx, off, 16));
    float ex = __expf(acc - mx);
    float sum = ex;
    for (int off = 8; off; off >>= 1) sum += __shfl_xor(sum, off, 16);
    float p = ex / sum;
    atomicAdd(&lme[e], p);
    float bv = acc; int bi = e;
    for (int off = 8; off; off >>= 1) {
        float ov = __shfl_xor(bv, off, 16);
        int   oi = __shfl_xor(bi, off, 16);
        if (ov > bv || (ov == bv && oi < bi)) { bv = ov; bi = oi; }
    }
    float pw = __shfl(p, bi, 16);
    if (e == 0) { eidx[tok] = bi; gp[tok] = pw; }
    __syncthreads();
    if (tid < 16) atomicAdd(&me_sums[tid], lme[tid]);
}

// single block, 1024 threads: ordered cumsum slot assignment + counts + l_aux
__global__ void moe_scan(const int* __restrict__ eidx, const float* __restrict__ me_sums,
                         int* __restrict__ slot, int* __restrict__ tos,
                         float* __restrict__ tail /* d_out + TOK*DIM */) {
    __shared__ int wcnt[16][16];
    __shared__ int base[16];
    const int tid = threadIdx.x, wid = tid >> 6, lane = tid & 63;
    if (tid < 16) base[tid] = 0;
    for (int i = tid; i < NE * CAP; i += 1024) tos[i] = -1;
    __syncthreads();
    const u64 below = ((u64)1 << lane) - 1;
    for (int chunk = 0; chunk < TOK / 1024; ++chunk) {
        int t = chunk * 1024 + tid;
        int e = eidx[t];
        int rank = 0;
#pragma unroll
        for (int ex = 0; ex < 16; ++ex) {
            u64 m = __ballot(e == ex);
            if (e == ex)    rank = __popcll(m & below);
            if (lane == ex) wcnt[wid][ex] = __popcll(m);
        }
        __syncthreads();
        int pre = base[e];
        for (int w = 0; w < wid; ++w) pre += wcnt[w][e];
        int s = pre + rank;
        slot[t] = s;
        if (s < CAP) tos[e * CAP + s] = t;
        __syncthreads();
        if (tid < 16) {
            int tot = 0;
            for (int w = 0; w < 16; ++w) tot += wcnt[w][tid];
            base[tid] += tot;
        }
        __syncthreads();
    }
    if (tid == 0) {
        float laux = 0.f;
        for (int e2 = 0; e2 < 16; ++e2) {
            float me = me_sums[e2] / (float)TOK;
            float ce = (float)base[e2] / (float)TOK;
            laux += me * ce;
        }
        tail[0] = laux * (float)NE;
    }
    if (tid < 16) tail[1 + tid] = (float)base[tid];
}

// one block per slot row: gather x[token] -> bf16 Xg[slot]; also zero dropped tokens
__global__ void moe_gather_zero(const float* __restrict__ x, const int* __restrict__ tos,
                                const int* __restrict__ slot, u16* __restrict__ Xg,
                                float* __restrict__ out) {
    const int b = blockIdx.x, tid = threadIdx.x;
    const int t = tos[b];
    float4 v = make_float4(0.f, 0.f, 0.f, 0.f);
    if (t >= 0) v = *(const float4*)(x + (size_t)t * DIM + tid * 4);
    u32 lo = (u32)f2bf(v.x) | ((u32)f2bf(v.y) << 16);
    u32 hi = (u32)f2bf(v.z) | ((u32)f2bf(v.w) << 16);
    *(uint2*)(Xg + (size_t)b * DIM + tid * 4) = make_uint2(lo, hi);
    if (slot[b] >= CAP)
        *(float4*)(out + (size_t)b * DIM + tid * 4) = make_float4(0.f, 0.f, 0.f, 0.f);
}

// ---------- GEMM1: H = gelu(Xg @ w1 + b1), bf16 out; B read f32-direct ----------
// 256x128 tile, BK=32, 8 waves (2Mx4N). A: bf16 Xg via gld16 (linear dest +
// gch source-swizzle). B: w1 [e][k][n] f32 -> 8 k-consecutive dwords of one
// column per thread -> f2bf -> ONE contiguous ds_write_b128 at tid*16B.
// B LDS layout is structurally identical to A's (same gch/rdoff involution,
// verified in R5). 4 buffers, 3 tiles in flight, counted vmcnt (20/10/0).
__global__ __launch_bounds__(512, 2) void moe_gemm1(const u16* __restrict__ Xg,
                                                    const float* __restrict__ w1,
                                                    const float* __restrict__ b1,
                                                    u16* __restrict__ H) {
    __shared__ alignas(16) u16 Als[4][8192];   // 64 KB
    __shared__ alignas(16) u16 Bls[4][4096];   // 32 KB
    const int tid = threadIdx.x, wave = tid >> 6, lane = tid & 63;
    const int flat = blockIdx.x;            // 0..1023
    const int xcd  = flat & 7;
    const int slot = flat >> 3;             // 0..127
    const int e    = xcd * 2 + (slot >> 6); // 2 experts per XCD
    const int tile = slot & 63;
    const int bm   = tile & 1;
    const int bn   = tile >> 1;             // 0..31
    const int r4   = lane >> 2;
    const int gch  = (lane & 3) ^ ((lane >> 3) & 3);
    const u16* aSrc = Xg + (size_t)(e * 512 + bm * 256 + wave * 16 + r4) * DIM + gch * 8;
    // B: column n = bn*128 + wave*16 + r4; k rows gch*8 + i (per K-tile + T*32)
    const float* bSrc = w1 + (size_t)e * DIM * NF + (size_t)gch * 8 * NF
                      + (bn * 128 + wave * 16 + r4);
    const int wm = wave & 1, wn = wave >> 1;
    const int fr = lane & 15, fq = lane >> 4;
    const int rdoff = fr * 32 + (fq ^ ((fr >> 1) & 3)) * 8;

    f32x4 acc[2][4][2] = {};
    float q[4][8];
    const int NT1 = DIM / 32;               // 32

#define ISSUE1(T, S) do { const int ko_ = (T) * 32; \
        u16* ad_ = &Als[(T) & 3][wave * 512]; \
        gld16(aSrc + ko_, ad_); gld16(aSrc + 128 * DIM + ko_, ad_ + 4096); \
        const float* bs_ = bSrc + (size_t)ko_ * NF; \
        _Pragma("unroll") for (int i_ = 0; i_ < 8; ++i_) q[S][i_] = bs_[(size_t)i_ * NF]; \
    } while (0)
#define BWR1(S) do { \
        u32 p0_ = (u32)f2bf(q[S][0]) | ((u32)f2bf(q[S][1]) << 16); \
        u32 p1_ = (u32)f2bf(q[S][2]) | ((u32)f2bf(q[S][3]) << 16); \
        u32 p2_ = (u32)f2bf(q[S][4]) | ((u32)f2bf(q[S][5]) << 16); \
        u32 p3_ = (u32)f2bf(q[S][6]) | ((u32)f2bf(q[S][7]) << 16); \
        *(uint4*)(&Bls[S][tid * 8]) = make_uint4(p0_, p1_, p2_, p3_); \
    } while (0)
#define COMP1(CUR) do { \
        const u16* Ab_ = &Als[CUR][0]; \
        const u16* Bb_ = &Bls[CUR][0]; \
        bf16x8 aF_[4], bF_[2]; \
        _Pragma("unroll") for (int j_ = 0; j_ < 2; ++j_) \
            bF_[j_] = *(const bf16x8*)(const void*)(Bb_ + (wn * 32 + j_ * 16) * 32 + rdoff); \
        _Pragma("unroll") for (int i_ = 0; i_ < 4; ++i_) \
            aF_[i_] = *(const bf16x8*)(const void*)(Ab_ + (wm * 128 + i_ * 16) * 32 + rdoff); \
        __builtin_amdgcn_s_setprio(1); \
        _Pragma("unroll") for (int i_ = 0; i_ < 4; ++i_) \
        _Pragma("unroll") for (int j_ = 0; j_ < 2; ++j_) \
            acc[0][i_][j_] = __builtin_amdgcn_mfma_f32_16x16x32_bf16(aF_[i_], bF_[j_], acc[0][i_][j_], 0, 0, 0); \
        __builtin_amdgcn_s_setprio(0); \
        _Pragma("unroll") for (int i_ = 0; i_ < 4; ++i_) \
            aF_[i_] = *(const bf16x8*)(const void*)(Ab_ + (wm * 128 + 64 + i_ * 16) * 32 + rdoff); \
        __builtin_amdgcn_s_setprio(1); \
        _Pragma("unroll") for (int i_ = 0; i_ < 4; ++i_) \
        _Pragma("unroll") for (int j_ = 0; j_ < 2; ++j_) \
            acc[1][i_][j_] = __builtin_amdgcn_mfma_f32_16x16x32_bf16(aF_[i_], bF_[j_], acc[1][i_][j_], 0, 0, 0); \
        __builtin_amdgcn_s_setprio(0); \
    } while (0)
#define STEP1(T, CUR, NXT, ISS) do { \
        if ((T) + 3 < NT1) ISSUE1((T) + 3, ISS); \
        if ((T) + 1 < NT1) { \
            if ((T) + 3 < NT1)      asm volatile("s_waitcnt vmcnt(20)" ::: "memory"); \
            else if ((T) + 2 < NT1) asm volatile("s_waitcnt vmcnt(10)" ::: "memory"); \
            else                    asm volatile("s_waitcnt vmcnt(0)"  ::: "memory"); \
            BWR1(NXT); \
        } \
        asm volatile("s_waitcnt lgkmcnt(0)" ::: "memory"); \
        __builtin_amdgcn_sched_barrier(0); \
        __builtin_amdgcn_s_barrier(); \
        __builtin_amdgcn_sched_barrier(0); \
        COMP1(CUR); \
        __builtin_amdgcn_sched_barrier(0); \
        __builtin_amdgcn_s_barrier(); \
    } while (0)

    ISSUE1(0, 0); ISSUE1(1, 1); ISSUE1(2, 2);
    asm volatile("s_waitcnt vmcnt(20)" ::: "memory");
    BWR1(0);
    asm volatile("s_waitcnt lgkmcnt(0)" ::: "memory");
    __builtin_amdgcn_s_barrier();
    for (int T = 0; T < NT1; T += 4) {
        STEP1(T + 0, 0, 1, 3);
        STEP1(T + 1, 1, 2, 0);
        STEP1(T + 2, 2, 3, 1);
        STEP1(T + 3, 3, 0, 2);
    }
#undef ISSUE1
#undef BWR1
#undef COMP1
#undef STEP1

    const int mBase = e * 512 + bm * 256 + wm * 128;
    const int nBase = bn * 128 + wn * 32;
#pragma unroll
    for (int j = 0; j < 2; ++j) {
        const int f = nBase + j * 16 + fr;
        const float bias = b1[e * NF + f];
#pragma unroll
        for (int qq = 0; qq < 2; ++qq)
#pragma unroll
            for (int i = 0; i < 4; ++i) {
                const int m0 = mBase + qq * 64 + i * 16 + fq * 4;
#pragma unroll
                for (int r = 0; r < 4; ++r) {
                    float v = acc[qq][i][j][r] + bias;
                    H[(size_t)(m0 + r) * NF + f] = f2bf(gelu_tanh(v));
                }
            }
    }
}

// ---------- GEMM2: out[token] = gate * (H @ w2 + b2); B = w2 f32-direct ----------
// Same structure as gemm1; K = NF (128 tiles), A row-stride NF, B row-stride DIM.
__global__ __launch_bounds__(512, 2) void moe_gemm2(const u16* __restrict__ H,
                                                    const float* __restrict__ w2,
                                                    const float* __restrict__ b2,
                                                    const int* __restrict__ tos,
                                                    const float* __restrict__ gp,
                                                    float* __restrict__ out) {
    __shared__ alignas(16) u16 Als[4][8192];   // 64 KB
    __shared__ alignas(16) u16 Bls[4][4096];   // 32 KB
    const int tid = threadIdx.x, wave = tid >> 6, lane = tid & 63;
    const int flat = blockIdx.x;            // 0..255
    const int xcd  = flat & 7;
    const int slot = flat >> 3;             // 0..31
    const int e    = xcd * 2 + (slot >> 4);
    const int tile = slot & 15;
    const int bm   = tile & 1;
    const int bn   = tile >> 1;             // 0..7
    const int r4   = lane >> 2;
    const int gch  = (lane & 3) ^ ((lane >> 3) & 3);
    const u16* aSrc = H + (size_t)(e * 512 + bm * 256 + wave * 16 + r4) * NF + gch * 8;
    const float* bSrc = w2 + (size_t)e * NF * DIM + (size_t)gch * 8 * DIM
                      + (bn * 128 + wave * 16 + r4);
    const int wm = wave & 1, wn = wave >> 1;
    const int fr = lane & 15, fq = lane >> 4;
    const int rdoff = fr * 32 + (fq ^ ((fr >> 1) & 3)) * 8;

    f32x4 acc[2][4][2] = {};
    float q[4][8];
    const int NT2 = NF / 32;                // 128

#define ISSUE2(T, S) do { const int ko_ = (T) * 32; \
        u16* ad_ = &Als[(T) & 3][wave * 512]; \
        gld16(aSrc + ko_, ad_); gld16(aSrc + (size_t)128 * NF + ko_, ad_ + 4096); \
        const float* bs_ = bSrc + (size_t)ko_ * DIM; \
        _Pragma("unroll") for (int i_ = 0; i_ < 8; ++i_) q[S][i_] = bs_[(size_t)i_ * DIM]; \
    } while (0)
#define BWR2(S) do { \
        u32 p0_ = (u32)f2bf(q[S][0]) | ((u32)f2bf(q[S][1]) << 16); \
        u32 p1_ = (u32)f2bf(q[S][2]) | ((u32)f2bf(q[S][3]) << 16); \
        u32 p2_ = (u32)f2bf(q[S][4]) | ((u32)f2bf(q[S][5]) << 16); \
        u32 p3_ = (u32)f2bf(q[S][6]) | ((u32)f2bf(q[S][7]) << 16); \
        *(uint4*)(&Bls[S][tid * 8]) = make_uint4(p0_, p1_, p2_, p3_); \
    } while (0)
#define COMP2(CUR) do { \
        const u16* Ab_ = &Als[CUR][0]; \
        const u16* Bb_ = &Bls[CUR][0]; \
        bf16x8 aF_[4], bF_[2]; \
        _Pragma("unroll") for (int j_ = 0; j_ < 2; ++j_) \
            bF_[j_] = *(const bf16x8*)(const void*)(Bb_ + (wn * 32 + j_ * 16) * 32 + rdoff); \
        _Pragma("unroll") for (int i_ = 0; i_ < 4; ++i_) \
            aF_[i_] = *(const bf16x8*)(const void*)(Ab_ + (wm * 128 + i_ * 16) * 32 + rdoff); \
        __builtin_amdgcn_s_setprio(1); \
        _Pragma("unroll") for (int i_ = 0; i_ < 4; ++i_) \
        _Pragma("unroll") for (int j_ = 0; j_ < 2; ++j_) \
            acc[0][i_][j_] = __builtin_amdgcn_mfma_f32_16x16x32_bf16(aF_[i_], bF_[j_], acc[0][i_][j_], 0, 0, 0); \
        __builtin_amdgcn_s_setprio(0); \
        _Pragma("unroll") for (int i_ = 0; i_ < 4; ++i_) \
            aF_[i_] = *(const bf16x8*)(const void*)(Ab_ + (wm * 128 + 64 + i_ * 16) * 32 + rdoff); \
        __builtin_amdgcn_s_setprio(1); \
        _Pragma("unroll") for (int i_ = 0; i_ < 4; ++i_) \
        _Pragma("unroll") for (int j_ = 0; j_ < 2; ++j_) \
            acc[1][i_][j_] = __builtin_amdgcn_mfma_f32_16x16x32_bf16(aF_[i_], bF_[j_], acc[1][i_][j_], 0, 0, 0); \
        __builtin_amdgcn_s_setprio(0); \
    } while (0)
#define STEP2(T, CUR, NXT, ISS) do { \
        if ((T) + 3 < NT2) ISSUE2((T) + 3, ISS); \
        if ((T) + 1 < NT2) { \
            if ((T) + 3 < NT2)      asm volatile("s_waitcnt vmcnt(20)" ::: "memory"); \
            else if ((T) + 2 < NT2) asm volatile("s_waitcnt vmcnt(10)" ::: "memory"); \
            else                    asm volatile("s_waitcnt vmcnt(0)"  ::: "memory"); \
            BWR2(NXT); \
        } \
        asm volatile("s_waitcnt lgkmcnt(0)" ::: "memory"); \
        __builtin_amdgcn_sched_barrier(0); \
        __builtin_amdgcn_s_barrier(); \
        __builtin_amdgcn_sched_barrier(0); \
        COMP2(CUR); \
        __builtin_amdgcn_sched_barrier(0); \
        __builtin_amdgcn_s_barrier(); \
    } while (0)

    ISSUE2(0, 0); ISSUE2(1, 1); ISSUE2(2, 2);
    asm volatile("s_waitcnt vmcnt(20)" ::: "memory");
    BWR2(0);
    asm volatile("s_waitcnt lgkmcnt(0)" ::: "memory");
    __builtin_amdgcn_s_barrier();
    for (int T = 0; T < NT2; T += 4) {
        STEP2(T + 0, 0, 1, 3);
        STEP2(T + 1, 1, 2, 0);
        STEP2(T + 2, 2, 3, 1);
        STEP2(T + 3, 3, 0, 2);
    }
#undef ISSUE2
#undef BWR2
#undef COMP2
#undef STEP2

    const int mBase = e * 512 + bm * 256 + wm * 128;
    const int nBase = bn * 128 + wn * 32;
#pragma unroll
    for (int qq = 0; qq < 2; ++qq)
#pragma unroll
        for (int i = 0; i < 4; ++i) {
#pragma unroll
            for (int r = 0; r < 4; ++r) {
                const int m = mBase + qq * 64 + i * 16 + fq * 4 + r;
                const int t = tos[m];
                if (t < 0) continue;
                const float g = gp[t];
#pragma unroll
                for (int j = 0; j < 2; ++j) {
                    const int d = nBase + j * 16 + fr;
                    out[(size_t)t * DIM + d] = g * (acc[qq][i][j][r] + b2[e * DIM + d]);
                }
            }
        }
}

// ---------- launch ----------
extern "C" void kernel_launch(void* const* d_in, const int* in_sizes, int n_in,
                              void* d_out, int out_size, void* d_ws, size_t ws_size,
                              hipStream_t stream) {
    const float* x  = (const float*)d_in[0];
    const float* wg = (const float*)d_in[1];
    const float* w1 = (const float*)d_in[2];
    const float* b1 = (const float*)d_in[3];
    const float* w2 = (const float*)d_in[4];
    const float* b2 = (const float*)d_in[5];
    float* out = (float*)d_out;

    char* ws = (char*)d_ws;
    const size_t XG_OFF = 0;                              // 16,777,216 B
    const size_t H_OFF  = XG_OFF + (size_t)TOK * DIM * 2; // 67,108,864 B
    const size_t SM_OFF = H_OFF + (size_t)TOK * NF * 2;
    u16* Xg = (u16*)(ws + XG_OFF);
    u16* H  = (u16*)(ws + H_OFF);
    int*   eidx = (int*)(ws + SM_OFF);                 // 32 KB
    float* gp   = (float*)(ws + SM_OFF + 32768);       // 32 KB
    int*   slot = (int*)(ws + SM_OFF + 65536);         // 32 KB
    int*   tos  = (int*)(ws + SM_OFF + 98304);         // 32 KB
    float* me   = (float*)(ws + SM_OFF + 131072);      // 64 B
    float* wgT  = (float*)(ws + SM_OFF + 131072 + 128);// 64 KB (16B aligned)

    float* tail = out + (size_t)TOK * DIM;             // [l_aux, exp_counts x16]

    moe_wgT<<<64, 256, 0, stream>>>(wg, wgT, me);
    moe_gate<<<TOK / 16, 256, 0, stream>>>(x, wgT, eidx, gp, me);
    moe_scan<<<1, 1024, 0, stream>>>(eidx, me, slot, tos, tail);
    moe_gather_zero<<<NE * CAP, 256, 0, stream>>>(x, tos, slot, Xg, out);
    moe_gemm1<<<1024, 512, 0, stream>>>(Xg, w1, b1, H);
    moe_gemm2<<<256, 512, 0, stream>>>(H, w2, b2, tos, gp, out);
}